// Round 1
// baseline (1011.893 us; speedup 1.0000x reference)
//
#include <hip/hip_runtime.h>
#include <math.h>

static constexpr int IMGS = 2;
static constexpr int H = 128, W = 128;
static constexpr int NP = H * W;           // 16384
static constexpr int KWIN = 30;            // quickshift window radius (ceil(3*10))
static constexpr int GR = 20;              // gaussian radius int(4*5+0.5)
static constexpr float INV = 0.005f;       // 0.5 / (10*10)
static constexpr int MAXSEG = 40;

// ---------------- rgb2lab (sRGB -> Lab, D65), CHW input -> float4 HW buffer ----
__global__ void k_lab(const float* __restrict__ x, float4* __restrict__ lab) {
#pragma clang fp contract(off)
  int i = blockIdx.x * blockDim.x + threadIdx.x;
  if (i >= IMGS * NP) return;
  int img = i / NP, p = i % NP;
  const float* base = x + img * 3 * NP;
  float rgb[3] = { base[p], base[NP + p], base[2 * NP + p] };
  float lin[3];
  for (int c = 0; c < 3; ++c) {
    float v = rgb[c];
    lin[c] = (v > 0.04045f) ? powf((v + 0.055f) / 1.055f, 2.4f) : (v / 12.92f);
  }
  const float M[3][3] = {{0.412453f, 0.357580f, 0.180423f},
                         {0.212671f, 0.715160f, 0.072169f},
                         {0.019334f, 0.119193f, 0.950227f}};
  const float wp[3] = {0.95047f, 1.0f, 1.08883f};
  float f[3];
  for (int j = 0; j < 3; ++j) {
    float s = lin[0] * M[j][0];
    s = s + lin[1] * M[j][1];
    s = s + lin[2] * M[j][2];
    float xyz = s / wp[j];
    f[j] = (xyz > 0.008856f) ? cbrtf(fmaxf(xyz, 1e-8f))
                             : (7.787f * xyz + (float)(16.0 / 116.0));
  }
  float L = 116.0f * f[1] - 16.0f;
  float a = 500.0f * (f[0] - f[1]);
  float b = 200.0f * (f[1] - f[2]);
  lab[i] = make_float4(L, a, b, 0.0f);
}

// ---------------- separable gaussian, symmetric padding ------------------------
__device__ inline void load_weights(float* w) {
  if (threadIdx.x == 0) {
    double k[2 * GR + 1];
    double s = 0.0;
    for (int i = -GR; i <= GR; ++i) {
      double t = (double)i / 5.0;
      double v = exp(-0.5 * t * t);
      k[i + GR] = v;
      s += v;
    }
    for (int i = 0; i < 2 * GR + 1; ++i) w[i] = (float)(k[i] / s);
  }
  __syncthreads();
}

__global__ void k_blurV(const float4* __restrict__ in, float4* __restrict__ out) {
#pragma clang fp contract(off)
  __shared__ float w[2 * GR + 1];
  load_weights(w);
  int i = blockIdx.x * blockDim.x + threadIdx.x;
  if (i >= IMGS * NP) return;
  int img = i / NP, p = i % NP;
  int y = p / W, xx = p % W;
  float a0 = 0.0f, a1 = 0.0f, a2 = 0.0f;   // Python sum() starts at 0; 0+x is exact
  for (int t = 0; t <= 2 * GR; ++t) {
    int yy = y - GR + t;
    if (yy < 0) yy = -yy - 1;
    if (yy >= H) yy = 2 * H - 1 - yy;
    float4 v = in[img * NP + yy * W + xx];
    float wt = w[t];
    a0 = a0 + wt * v.x;
    a1 = a1 + wt * v.y;
    a2 = a2 + wt * v.z;
  }
  out[i] = make_float4(a0, a1, a2, 0.0f);
}

__global__ void k_blurH(const float4* __restrict__ in, float4* __restrict__ out) {
#pragma clang fp contract(off)
  __shared__ float w[2 * GR + 1];
  load_weights(w);
  int i = blockIdx.x * blockDim.x + threadIdx.x;
  if (i >= IMGS * NP) return;
  int img = i / NP, p = i % NP;
  int y = p / W, xx = p % W;
  float a0 = 0.0f, a1 = 0.0f, a2 = 0.0f;
  for (int t = 0; t <= 2 * GR; ++t) {
    int xq = xx - GR + t;
    if (xq < 0) xq = -xq - 1;
    if (xq >= W) xq = 2 * W - 1 - xq;
    float4 v = in[img * NP + y * W + xq];
    float wt = w[t];
    a0 = a0 + wt * v.x;
    a1 = a1 + wt * v.y;
    a2 = a2 + wt * v.z;
  }
  out[i] = make_float4(a0, a1, a2, 0.0f);
}

// ---------------- density: sequential row-major accumulation (order matters) ---
__global__ void k_dens(const float4* __restrict__ feat, float* __restrict__ dens) {
#pragma clang fp contract(off)
  int i = blockIdx.x * blockDim.x + threadIdx.x;
  if (i >= IMGS * NP) return;
  int img = i / NP, p = i % NP;
  int y = p / W, x = p % W;
  const float4* fimg = feat + img * NP;
  float4 fc = fimg[p];
  float acc = 0.0f;
  int c0 = (x >= KWIN) ? -KWIN : -x;
  int c1 = (x + KWIN <= W - 1) ? KWIN : (W - 1 - x);
  for (int dr = -KWIN; dr <= KWIN; ++dr) {
    int ny = y + dr;
    if (ny < 0 || ny >= H) continue;       // masked terms add exact 0.0 in ref
    int spr = dr * dr;
    const float4* row = fimg + ny * W + x;
    for (int dc = c0; dc <= c1; ++dc) {
      float4 nb = row[dc];
      float d0 = fc.x - nb.x, d1 = fc.y - nb.y, d2 = fc.z - nb.z;
      float d = (d0 * d0 + d1 * d1) + d2 * d2;
      d = d + (float)(spr + dc * dc);
      acc = acc + expf(-d * INV);
    }
  }
  dens[i] = acc;
}

// ---------------- parent: nearest strictly-higher-density neighbor -------------
__global__ void k_par(const float4* __restrict__ feat, const float* __restrict__ dens,
                      int* __restrict__ parent) {
#pragma clang fp contract(off)
  int i = blockIdx.x * blockDim.x + threadIdx.x;
  if (i >= IMGS * NP) return;
  int img = i / NP, p = i % NP;
  int y = p / W, x = p % W;
  const float4* fimg = feat + img * NP;
  const float* dimg = dens + img * NP;
  float4 fc = fimg[p];
  float dcen = dimg[p];
  float bestd = __builtin_inff();
  int bestp = p;
  int c0 = (x >= KWIN) ? -KWIN : -x;
  int c1 = (x + KWIN <= W - 1) ? KWIN : (W - 1 - x);
  for (int dr = -KWIN; dr <= KWIN; ++dr) {
    int ny = y + dr;
    if (ny < 0 || ny >= H) continue;       // ref pads dens with -inf: never qualifies
    int spr = dr * dr;
    int rowoff = ny * W + x;
    for (int dc = c0; dc <= c1; ++dc) {
      int q = rowoff + dc;
      float nd = dimg[q];
      float4 nb = fimg[q];
      float d0 = fc.x - nb.x, d1 = fc.y - nb.y, d2 = fc.z - nb.z;
      float d = (d0 * d0 + d1 * d1) + d2 * d2;
      d = d + (float)(spr + dc * dc);
      if (nd > dcen && d < bestd) {        // strict <: first-in-row-major wins ties
        bestd = d;
        bestp = q;
      }
    }
  }
  if (bestd > 400.0f) bestp = p;           // sqrt(best_d) > max_dist
  parent[i] = bestp;
}

// ---------------- root chase + presence marking --------------------------------
__global__ void k_root(const int* __restrict__ parent, int* __restrict__ root,
                       int* __restrict__ pres) {
  int i = blockIdx.x * blockDim.x + threadIdx.x;
  if (i >= IMGS * NP) return;
  int img = i / NP, p = i % NP;
  const int* par = parent + img * NP;
  int r = par[p];
  for (int it = 0; it < NP; ++it) {        // chains strictly increase density => acyclic
    int pr = par[r];
    if (pr == r) break;
    r = pr;
  }
  root[i] = r;                             // image-local root index
  pres[img * NP + r] = 1;
}

// ---------------- per-image inclusive scan of presence flags -------------------
__global__ void k_scan(int* __restrict__ pres) {
  __shared__ int part[256];
  int img = blockIdx.x;
  int t = threadIdx.x;                     // 256 threads x 64 elements
  int* a = pres + img * NP;
  int base = t * 64;
  int s = 0;
  for (int j = 0; j < 64; ++j) s += a[base + j];
  part[t] = s;
  __syncthreads();
  for (int off = 1; off < 256; off <<= 1) {
    int add = (t >= off) ? part[t - off] : 0;
    __syncthreads();
    part[t] += add;
    __syncthreads();
  }
  int run = part[t] - s;                   // exclusive prefix for this chunk
  for (int j = 0; j < 64; ++j) {
    run += a[base + j];
    a[base + j] = run;
  }
}

// ---------------- final labels --------------------------------------------------
__global__ void k_label(const int* __restrict__ root, const int* __restrict__ cums,
                        int* __restrict__ out) {
  int i = blockIdx.x * blockDim.x + threadIdx.x;
  if (i >= IMGS * NP) return;
  int img = i / NP;
  int r = root[i];
  int lab = cums[img * NP + r] - 1;
  out[i] = (lab < MAXSEG - 1) ? lab : (MAXSEG - 1);
}

extern "C" void kernel_launch(void* const* d_in, const int* in_sizes, int n_in,
                              void* d_out, int out_size, void* d_ws, size_t ws_size,
                              hipStream_t stream) {
  const float* x = (const float*)d_in[0];
  int* out = (int*)d_out;
  char* ws = (char*)d_ws;

  // workspace layout (1.5 MB total)
  float4* bufA = (float4*)(ws);                       // 2*16384*16 = 524288
  float4* bufB = (float4*)(ws + 524288);              // 524288
  float* dens  = (float*)(ws + 1048576);              // 131072
  int* parent  = (int*)(ws + 1048576 + 131072);       // 131072
  int* root    = (int*)(ws + 1048576 + 2 * 131072);   // 131072
  int* pres    = (int*)(ws + 1048576 + 3 * 131072);   // 131072

  const int total = IMGS * NP;
  k_lab<<<total / 256, 256, 0, stream>>>(x, bufA);
  k_blurV<<<total / 256, 256, 0, stream>>>(bufA, bufB);
  k_blurH<<<total / 256, 256, 0, stream>>>(bufB, bufA);
  k_dens<<<total / 64, 64, 0, stream>>>(bufA, dens);
  k_par<<<total / 64, 64, 0, stream>>>(bufA, dens, parent);
  hipMemsetAsync(pres, 0, total * sizeof(int), stream);
  k_root<<<total / 256, 256, 0, stream>>>(parent, root, pres);
  k_scan<<<IMGS, 256, 0, stream>>>(pres);
  k_label<<<total / 256, 256, 0, stream>>>(root, pres, out);
}

// Round 2
// 490.588 us; speedup vs baseline: 2.0626x; 2.0626x over previous
//
#include <hip/hip_runtime.h>
#include <math.h>

static constexpr int IMGS = 2;
static constexpr int H = 128, W = 128;
static constexpr int NP = H * W;           // 16384
static constexpr int KWIN = 30;            // quickshift window radius (ceil(3*10))
static constexpr int GR = 20;              // gaussian radius int(4*5+0.5)
static constexpr float INV = 0.005f;       // 0.5 / (10*10)
static constexpr int MAXSEG = 40;

// padded layouts: row stride 192, cols [30,158) hold the image, pads are sentinels
static constexpr int PSTR = 192;
static constexpr int PIMG = H * PSTR;      // 24576 elements per image (float4 for PF, float for PD)

// ---------------- rgb2lab (sRGB -> Lab, D65), CHW input -> float4 HW buffer ----
__global__ void k_lab(const float* __restrict__ x, float4* __restrict__ lab) {
#pragma clang fp contract(off)
  int i = blockIdx.x * blockDim.x + threadIdx.x;
  if (i >= IMGS * NP) return;
  int img = i / NP, p = i % NP;
  const float* base = x + img * 3 * NP;
  float rgb[3] = { base[p], base[NP + p], base[2 * NP + p] };
  float lin[3];
  for (int c = 0; c < 3; ++c) {
    float v = rgb[c];
    lin[c] = (v > 0.04045f) ? powf((v + 0.055f) / 1.055f, 2.4f) : (v / 12.92f);
  }
  const float M[3][3] = {{0.412453f, 0.357580f, 0.180423f},
                         {0.212671f, 0.715160f, 0.072169f},
                         {0.019334f, 0.119193f, 0.950227f}};
  const float wp[3] = {0.95047f, 1.0f, 1.08883f};
  float f[3];
  for (int j = 0; j < 3; ++j) {
    float s = lin[0] * M[j][0];
    s = s + lin[1] * M[j][1];
    s = s + lin[2] * M[j][2];
    float xyz = s / wp[j];
    f[j] = (xyz > 0.008856f) ? cbrtf(fmaxf(xyz, 1e-8f))
                             : (7.787f * xyz + (float)(16.0 / 116.0));
  }
  float L = 116.0f * f[1] - 16.0f;
  float a = 500.0f * (f[0] - f[1]);
  float b = 200.0f * (f[1] - f[2]);
  lab[i] = make_float4(L, a, b, 0.0f);
}

// ---------------- separable gaussian, symmetric padding ------------------------
// weight computation identical to round-1 (passed absmax 0.0) — do not touch
__device__ inline void load_weights(float* w) {
  if (threadIdx.x == 0) {
    double k[2 * GR + 1];
    double s = 0.0;
    for (int i = -GR; i <= GR; ++i) {
      double t = (double)i / 5.0;
      double v = exp(-0.5 * t * t);
      k[i + GR] = v;
      s += v;
    }
    for (int i = 0; i < 2 * GR + 1; ++i) w[i] = (float)(k[i] / s);
  }
  __syncthreads();
}

__global__ void k_blurV(const float4* __restrict__ in, float4* __restrict__ out) {
#pragma clang fp contract(off)
  __shared__ float w[2 * GR + 1];
  load_weights(w);
  int i = blockIdx.x * blockDim.x + threadIdx.x;
  if (i >= IMGS * NP) return;
  int img = i / NP, p = i % NP;
  int y = p / W, xx = p % W;
  float a0 = 0.0f, a1 = 0.0f, a2 = 0.0f;
  for (int t = 0; t <= 2 * GR; ++t) {
    int yy = y - GR + t;
    if (yy < 0) yy = -yy - 1;
    if (yy >= H) yy = 2 * H - 1 - yy;
    float4 v = in[img * NP + yy * W + xx];
    float wt = w[t];
    a0 = a0 + wt * v.x;
    a1 = a1 + wt * v.y;
    a2 = a2 + wt * v.z;
  }
  out[i] = make_float4(a0, a1, a2, 0.0f);
}

// writes into PADDED feature buffer (interior cols 30..157)
__global__ void k_blurH(const float4* __restrict__ in, float4* __restrict__ pf) {
#pragma clang fp contract(off)
  __shared__ float w[2 * GR + 1];
  load_weights(w);
  int i = blockIdx.x * blockDim.x + threadIdx.x;
  if (i >= IMGS * NP) return;
  int img = i / NP, p = i % NP;
  int y = p / W, xx = p % W;
  float a0 = 0.0f, a1 = 0.0f, a2 = 0.0f;
  for (int t = 0; t <= 2 * GR; ++t) {
    int xq = xx - GR + t;
    if (xq < 0) xq = -xq - 1;
    if (xq >= W) xq = 2 * W - 1 - xq;
    float4 v = in[img * NP + y * W + xq];
    float wt = w[t];
    a0 = a0 + wt * v.x;
    a1 = a1 + wt * v.y;
    a2 = a2 + wt * v.z;
  }
  pf[img * PIMG + y * PSTR + (xx + KWIN)] = make_float4(a0, a1, a2, 0.0f);
}

// ---------------- pad-fill kernels ---------------------------------------------
// PF sentinel 1e6: color dist ~3e12 -> exp underflows to exactly +0.0 == ref's m=0 term
__global__ void k_fillPF(float4* __restrict__ pf) {
  int i = blockIdx.x * blockDim.x + threadIdx.x;
  if (i < IMGS * PIMG) pf[i] = make_float4(1e6f, 1e6f, 1e6f, 1e6f);
}
// PD sentinel -inf: matches reference's pd = pad(dens, constant=-inf)
__global__ void k_fillPD(float* __restrict__ pd) {
  int i = blockIdx.x * blockDim.x + threadIdx.x;
  if (i < IMGS * PIMG) pd[i] = -__builtin_inff();
}

// ---------------- density: sequential row-major accumulation (order matters) ---
__global__ __launch_bounds__(64, 1)
void k_dens(const float4* __restrict__ pf, float* __restrict__ pd) {
#pragma clang fp contract(off)
  int i = blockIdx.x * blockDim.x + threadIdx.x;
  if (i >= IMGS * NP) return;
  int img = i / NP, p = i % NP;
  int y = p / W, x = p % W;
  const float4* fimg = pf + img * PIMG;
  float4 fc = fimg[y * PSTR + (x + KWIN)];
  float acc = 0.0f;
#pragma unroll 1
  for (int dr = -KWIN; dr <= KWIN; ++dr) {
    int ny = y + dr;
    if ((unsigned)ny >= (unsigned)H) continue;  // wave-uniform; skipped terms add exact 0.0
    int spr = dr * dr;
    const float4* row = fimg + ny * PSTR + (x + KWIN);
#pragma unroll
    for (int dc = -KWIN; dc <= KWIN; ++dc) {
      float4 nb = row[dc];
      float d0 = fc.x - nb.x, d1 = fc.y - nb.y, d2 = fc.z - nb.z;
      float d = (d0 * d0 + d1 * d1) + d2 * d2;
      d = d + (float)(spr + dc * dc);
      acc = acc + expf(-d * INV);   // pad cols: d~3e12 -> exp == +0.0 exactly
    }
  }
  pd[img * PIMG + y * PSTR + (x + KWIN)] = acc;
}

// ---------------- parent: nearest strictly-higher-density neighbor -------------
__global__ __launch_bounds__(64, 1)
void k_par(const float4* __restrict__ pf, const float* __restrict__ pd,
           int* __restrict__ parent) {
#pragma clang fp contract(off)
  int i = blockIdx.x * blockDim.x + threadIdx.x;
  if (i >= IMGS * NP) return;
  int img = i / NP, p = i % NP;
  int y = p / W, x = p % W;
  const float4* fimg = pf + img * PIMG;
  const float* dimg = pd + img * PIMG;
  float4 fc = fimg[y * PSTR + (x + KWIN)];
  float dcen = dimg[y * PSTR + (x + KWIN)];
  float bestd = __builtin_inff();
  int bestp = p;
#pragma unroll 1
  for (int dr = -KWIN; dr <= KWIN; ++dr) {
    int ny = y + dr;
    if ((unsigned)ny >= (unsigned)H) continue;  // ref: nd = -inf there, never qualifies
    int spr = dr * dr;
    const float4* row = fimg + ny * PSTR + (x + KWIN);
    const float* drow = dimg + ny * PSTR + (x + KWIN);
    int qbase = ny * W + x;                     // un-padded flat index base
#pragma unroll
    for (int dc = -KWIN; dc <= KWIN; ++dc) {
      float nd = drow[dc];                      // pad cols: -inf
      float4 nb = row[dc];
      float d0 = fc.x - nb.x, d1 = fc.y - nb.y, d2 = fc.z - nb.z;
      float d = (d0 * d0 + d1 * d1) + d2 * d2;
      d = d + (float)(spr + dc * dc);
      int better = (nd > dcen) & (d < bestd);   // strict <: first-in-row-major wins ties
      bestd = better ? d : bestd;
      bestp = better ? (qbase + dc) : bestp;
    }
  }
  if (bestd > 400.0f) bestp = p;                // sqrt(best_d) > max_dist
  parent[i] = bestp;
}

// ---------------- root chase + presence marking --------------------------------
__global__ void k_root(const int* __restrict__ parent, int* __restrict__ root,
                       int* __restrict__ pres) {
  int i = blockIdx.x * blockDim.x + threadIdx.x;
  if (i >= IMGS * NP) return;
  int img = i / NP, p = i % NP;
  const int* par = parent + img * NP;
  int r = par[p];
  for (int it = 0; it < NP; ++it) {             // chains strictly increase density => acyclic
    int pr = par[r];
    if (pr == r) break;
    r = pr;
  }
  root[i] = r;
  pres[img * NP + r] = 1;
}

// ---------------- per-image inclusive scan of presence flags -------------------
__global__ void k_scan(int* __restrict__ pres) {
  __shared__ int part[256];
  int img = blockIdx.x;
  int t = threadIdx.x;                          // 256 threads x 64 elements
  int* a = pres + img * NP;
  int base = t * 64;
  int s = 0;
  for (int j = 0; j < 64; ++j) s += a[base + j];
  part[t] = s;
  __syncthreads();
  for (int off = 1; off < 256; off <<= 1) {
    int add = (t >= off) ? part[t - off] : 0;
    __syncthreads();
    part[t] += add;
    __syncthreads();
  }
  int run = part[t] - s;
  for (int j = 0; j < 64; ++j) {
    run += a[base + j];
    a[base + j] = run;
  }
}

// ---------------- final labels --------------------------------------------------
__global__ void k_label(const int* __restrict__ root, const int* __restrict__ cums,
                        int* __restrict__ out) {
  int i = blockIdx.x * blockDim.x + threadIdx.x;
  if (i >= IMGS * NP) return;
  int img = i / NP;
  int r = root[i];
  int lab = cums[img * NP + r] - 1;
  out[i] = (lab < MAXSEG - 1) ? lab : (MAXSEG - 1);
}

extern "C" void kernel_launch(void* const* d_in, const int* in_sizes, int n_in,
                              void* d_out, int out_size, void* d_ws, size_t ws_size,
                              hipStream_t stream) {
  const float* x = (const float*)d_in[0];
  int* out = (int*)d_out;
  char* ws = (char*)d_ws;

  // workspace layout (~1.94 MB); bufA region is reused for parent/root/pres
  float4* pf   = (float4*)(ws);                         // 2*24576*16 = 786432
  float*  pd   = (float*)(ws + 786432);                 // 2*24576*4  = 196608
  float4* bufA = (float4*)(ws + 983040);                // 524288 (lab out / blurV in)
  float4* bufB = (float4*)(ws + 1507328);               // 524288 (blurV out / blurH in)
  int* parent  = (int*)(ws + 983040);                   // alias bufA (dead after blurV)
  int* root    = (int*)(ws + 983040 + 131072);
  int* pres    = (int*)(ws + 983040 + 262144);

  const int total = IMGS * NP;                          // 32768
  const int ptotal = IMGS * PIMG;                       // 49152

  k_fillPF<<<(ptotal + 255) / 256, 256, 0, stream>>>(pf);
  k_fillPD<<<(ptotal + 255) / 256, 256, 0, stream>>>(pd);
  k_lab<<<total / 256, 256, 0, stream>>>(x, bufA);
  k_blurV<<<total / 256, 256, 0, stream>>>(bufA, bufB);
  k_blurH<<<total / 256, 256, 0, stream>>>(bufB, pf);
  k_dens<<<total / 64, 64, 0, stream>>>(pf, pd);
  k_par<<<total / 64, 64, 0, stream>>>(pf, pd, parent);
  hipMemsetAsync(pres, 0, total * sizeof(int), stream);
  k_root<<<total / 256, 256, 0, stream>>>(parent, root, pres);
  k_scan<<<IMGS, 256, 0, stream>>>(pres);
  k_label<<<total / 256, 256, 0, stream>>>(root, pres, out);
}